// Round 2
// baseline (1351.019 us; speedup 1.0000x reference)
//
#include <hip/hip_runtime.h>
#include <hip/hip_bf16.h>
#include <math.h>

#define BB 8
#define LL 4096
#define DD 512

// ---------------------------------------------------------------------------
// K1: logits[b,l] = gelu_erf(hidden[b,l,:] @ W1 + b1) @ W2 + b2
// 64 rows/block, 512 threads (8 waves). Wave rg owns 8 rows; lane owns 8 cols
// (two contiguous float4 groups). fp32 accumulation throughout.
// ---------------------------------------------------------------------------
__global__ __launch_bounds__(512, 2)
void k_logits(const float* __restrict__ hidden, const float* __restrict__ W1,
              const float* __restrict__ b1, const float* __restrict__ W2,
              const float* __restrict__ b2, float* __restrict__ logits) {
    __shared__ float xs[64][16];
    __shared__ float wsm[16][512];
    const int tid  = threadIdx.x;
    const int rg   = tid >> 6;     // wave 0..7
    const int lane = tid & 63;
    const int rowBase = blockIdx.x * 64;

    float acc[8][8];
#pragma unroll
    for (int i = 0; i < 8; i++)
#pragma unroll
        for (int j = 0; j < 8; j++) acc[i][j] = 0.f;

    for (int kt = 0; kt < DD; kt += 16) {
        // stage x tile: 64 rows x 16 k
        if (tid < 256) {
            int row = tid >> 2;
            int k4  = tid & 3;
            const float4 v = *reinterpret_cast<const float4*>(
                &hidden[(size_t)(rowBase + row) * DD + kt + k4 * 4]);
            *reinterpret_cast<float4*>(&xs[row][k4 * 4]) = v;
        }
        // stage W1 tile: 16 x 512
#pragma unroll
        for (int i = 0; i < 4; i++) {
            int idx = tid + i * 512;      // 0..2047 float4s
            int kk  = idx >> 7;
            int j4  = idx & 127;
            const float4 v = *reinterpret_cast<const float4*>(
                &W1[(size_t)(kt + kk) * DD + j4 * 4]);
            *reinterpret_cast<float4*>(&wsm[kk][j4 * 4]) = v;
        }
        __syncthreads();
#pragma unroll
        for (int kk4 = 0; kk4 < 4; kk4++) {
            float4 xv[8];
#pragma unroll
            for (int i = 0; i < 8; i++)
                xv[i] = *reinterpret_cast<const float4*>(&xs[rg * 8 + i][kk4 * 4]);
#pragma unroll
            for (int kq = 0; kq < 4; kq++) {
                float4 wa = *reinterpret_cast<const float4*>(&wsm[kk4 * 4 + kq][lane * 4]);
                float4 wb = *reinterpret_cast<const float4*>(&wsm[kk4 * 4 + kq][256 + lane * 4]);
#pragma unroll
                for (int i = 0; i < 8; i++) {
                    float x = (kq == 0) ? xv[i].x : (kq == 1) ? xv[i].y
                              : (kq == 2) ? xv[i].z : xv[i].w;
                    acc[i][0] += x * wa.x; acc[i][1] += x * wa.y;
                    acc[i][2] += x * wa.z; acc[i][3] += x * wa.w;
                    acc[i][4] += x * wb.x; acc[i][5] += x * wb.y;
                    acc[i][6] += x * wb.z; acc[i][7] += x * wb.w;
                }
            }
        }
        __syncthreads();
    }

    // epilogue: +b1, exact-erf gelu, dot with W2, wave-reduce, +b2
    float4 b1a = *reinterpret_cast<const float4*>(&b1[lane * 4]);
    float4 b1b = *reinterpret_cast<const float4*>(&b1[256 + lane * 4]);
    float4 w2a = *reinterpret_cast<const float4*>(&W2[lane * 4]);
    float4 w2b = *reinterpret_cast<const float4*>(&W2[256 + lane * 4]);
    const float bias2 = b2[0];
#pragma unroll
    for (int i = 0; i < 8; i++) {
        float vals[8] = {acc[i][0] + b1a.x, acc[i][1] + b1a.y, acc[i][2] + b1a.z,
                         acc[i][3] + b1a.w, acc[i][4] + b1b.x, acc[i][5] + b1b.y,
                         acc[i][6] + b1b.z, acc[i][7] + b1b.w};
        float w2v[8] = {w2a.x, w2a.y, w2a.z, w2a.w, w2b.x, w2b.y, w2b.z, w2b.w};
        float p = 0.f;
#pragma unroll
        for (int j = 0; j < 8; j++) {
            float v = vals[j];
            float g = 0.5f * v * (1.0f + erff(v * 0.70710678118654752f));
            p += g * w2v[j];
        }
#pragma unroll
        for (int off = 32; off; off >>= 1) p += __shfl_xor(p, off, 64);
        if (lane == 0) logits[rowBase + rg * 8 + i] = p + bias2;
    }
}

// ---------------------------------------------------------------------------
// K2: per-batch sigmoid/mask/forced-last, block-wide exclusive scan of hard,
// record boundary positions. Writes masked_probs, shortened_lengths,
// num_boundaries directly (fp32 — reference outputs are float32).
// ---------------------------------------------------------------------------
__global__ __launch_bounds__(1024)
void k_bound(const float* __restrict__ logits, const float* __restrict__ lengths,
             float* __restrict__ out, int S,
             int* __restrict__ nseg, int* __restrict__ bpos) {
    const int b   = blockIdx.x;
    const int tid = threadIdx.x;          // 1024 threads, 4 t each
    const float alenf = lengths[b] * (float)LL;
    const int alen = (int)alenf;          // truncation, matches .astype(int32)
    int last = alen - 1;
    if (last < 0) last = 0;
    if (last > LL - 1) last = LL - 1;

    float* out_mp = out + (size_t)BB * S * DD;

    int h[4];
    float4 mp_pack;
    float* mpp = reinterpret_cast<float*>(&mp_pack);
#pragma unroll
    for (int i = 0; i < 4; i++) {
        int t = tid * 4 + i;
        float lg = logits[b * LL + t];
        float prob = 1.0f / (1.0f + expf(-lg));
        bool valid = t < alen;
        float mp = valid ? prob : 0.0f;
        mpp[i] = mp;
        int hd = (prob > 0.5f && valid) ? 1 : 0;
        if (t == last) hd = 1;
        h[i] = hd;
    }
    *reinterpret_cast<float4*>(&out_mp[b * LL + tid * 4]) = mp_pack;

    int s4 = h[0] + h[1] + h[2] + h[3];
    const int lane = tid & 63;
    const int wave = tid >> 6;            // 0..15
    int incl = s4;
#pragma unroll
    for (int off = 1; off < 64; off <<= 1) {
        int v = __shfl_up(incl, off, 64);
        if (lane >= off) incl += v;
    }
    __shared__ int wsum[16];
    __shared__ int woff[17];
    if (lane == 63) wsum[wave] = incl;
    __syncthreads();
    if (tid == 0) {
        int r = 0;
        for (int w = 0; w < 16; w++) { woff[w] = r; r += wsum[w]; }
        woff[16] = r;
    }
    __syncthreads();
    int ex = woff[wave] + incl - s4;      // exclusive prefix of this thread's 1st elem
#pragma unroll
    for (int i = 0; i < 4; i++) {
        int t = tid * 4 + i;
        if (h[i]) { bpos[b * LL + ex] = t; ex++; }
    }
    if (tid == 0) {
        int total = woff[16];
        nseg[b] = total;
        float* out_sl = out + (size_t)BB * S * DD + (size_t)BB * LL;
        float* out_nb = out_sl + BB;
        out_nb[b] = (float)total;
        int denom = (S > 1) ? S : 1;
        out_sl[b] = (float)total / (float)denom;
    }
}

// ---------------------------------------------------------------------------
// K3: segment mean-pool. One wave per (b,s); segment span from bpos.
// Segment s<n: [prev_bpos+1, bpos[s]]; s==n: tail (invalid region); s>n: zero.
// ---------------------------------------------------------------------------
__global__ __launch_bounds__(256)
void k_pool(const float* __restrict__ hidden, const int* __restrict__ nseg,
            const int* __restrict__ bpos, float* __restrict__ out_pooled,
            int S) {
    const int tid  = threadIdx.x;
    const int wave = tid >> 6;            // 0..3
    const int lane = tid & 63;
    int gs = blockIdx.x * 4 + wave;
    if (gs >= BB * S) return;
    int b = gs / S;
    int s = gs - b * S;
    int n = nseg[b];

    float4 a0 = {0.f, 0.f, 0.f, 0.f};
    float4 a1 = {0.f, 0.f, 0.f, 0.f};
    int start = 0, end = -1;
    if (s < n) {
        end   = bpos[b * LL + s];
        start = (s == 0) ? 0 : bpos[b * LL + s - 1] + 1;
    } else if (s == n) {                  // n >= 1 always (forced last boundary)
        start = bpos[b * LL + n - 1] + 1;
        end   = LL - 1;
    }
    int cnt = end - start + 1;
    if (cnt > 0) {
        const float* base = hidden + ((size_t)b * LL + start) * DD;
        for (int t = 0; t < cnt; t++) {
            float4 v0 = *reinterpret_cast<const float4*>(base + (size_t)t * DD + lane * 4);
            float4 v1 = *reinterpret_cast<const float4*>(base + (size_t)t * DD + 256 + lane * 4);
            a0.x += v0.x; a0.y += v0.y; a0.z += v0.z; a0.w += v0.w;
            a1.x += v1.x; a1.y += v1.y; a1.z += v1.z; a1.w += v1.w;
        }
        float inv = 1.0f / (float)cnt;
        a0.x *= inv; a0.y *= inv; a0.z *= inv; a0.w *= inv;
        a1.x *= inv; a1.y *= inv; a1.z *= inv; a1.w *= inv;
    }
    float* dst = out_pooled + ((size_t)b * S + s) * DD;
    *reinterpret_cast<float4*>(&dst[lane * 4]) = a0;
    *reinterpret_cast<float4*>(&dst[256 + lane * 4]) = a1;
}

// ---------------------------------------------------------------------------
extern "C" void kernel_launch(void* const* d_in, const int* in_sizes, int n_in,
                              void* d_out, int out_size, void* d_ws, size_t ws_size,
                              hipStream_t stream) {
    const float* hidden  = (const float*)d_in[0];
    const float* lengths = (const float*)d_in[1];
    const float* W1      = (const float*)d_in[2];
    const float* b1      = (const float*)d_in[3];
    const float* W2      = (const float*)d_in[4];
    const float* b2      = (const float*)d_in[5];
    float* out           = (float*)d_out;

    const int S = (out_size - BB * LL - 2 * BB) / (BB * DD);

    float* logits = (float*)d_ws;                                   // B*L f32
    int*   bpos   = (int*)((char*)d_ws + (size_t)BB * LL * 4);      // B*L i32
    int*   nseg   = (int*)((char*)d_ws + (size_t)2 * BB * LL * 4);  // B i32

    k_logits<<<(BB * LL) / 64, 512, 0, stream>>>(hidden, W1, b1, W2, b2, logits);
    k_bound<<<BB, 1024, 0, stream>>>(logits, lengths, out, S, nseg, bpos);
    int nblocks = (BB * S + 3) / 4;
    k_pool<<<nblocks, 256, 0, stream>>>(hidden, nseg, bpos, out, S);
}

// Round 3
// 359.049 us; speedup vs baseline: 3.7628x; 3.7628x over previous
//
#include <hip/hip_runtime.h>
#include <hip/hip_bf16.h>
#include <math.h>

#define BB 8
#define LL 4096
#define DD 512
#define CH 32            // positions per pooling chunk (one wave each)

// ---------------------------------------------------------------------------
// K1: logits[b,l] = gelu_erf(hidden[b,l,:] @ W1 + b1) @ W2 + b2
// 64 rows/block, 512 threads (8 waves). Wave rg owns 8 rows; lane owns 8 cols.
// fp32 accumulation throughout (no fp32 MFMA on CDNA4 -> vector ALU).
// ---------------------------------------------------------------------------
__global__ __launch_bounds__(512, 2)
void k_logits(const float* __restrict__ hidden, const float* __restrict__ W1,
              const float* __restrict__ b1, const float* __restrict__ W2,
              const float* __restrict__ b2, float* __restrict__ logits) {
    __shared__ float xs[64][16];
    __shared__ float wsm[16][512];
    const int tid  = threadIdx.x;
    const int rg   = tid >> 6;     // wave 0..7
    const int lane = tid & 63;
    const int rowBase = blockIdx.x * 64;

    float acc[8][8];
#pragma unroll
    for (int i = 0; i < 8; i++)
#pragma unroll
        for (int j = 0; j < 8; j++) acc[i][j] = 0.f;

    for (int kt = 0; kt < DD; kt += 16) {
        if (tid < 256) {
            int row = tid >> 2;
            int k4  = tid & 3;
            const float4 v = *reinterpret_cast<const float4*>(
                &hidden[(size_t)(rowBase + row) * DD + kt + k4 * 4]);
            *reinterpret_cast<float4*>(&xs[row][k4 * 4]) = v;
        }
#pragma unroll
        for (int i = 0; i < 4; i++) {
            int idx = tid + i * 512;      // 0..2047 float4s
            int kk  = idx >> 7;
            int j4  = idx & 127;
            const float4 v = *reinterpret_cast<const float4*>(
                &W1[(size_t)(kt + kk) * DD + j4 * 4]);
            *reinterpret_cast<float4*>(&wsm[kk][j4 * 4]) = v;
        }
        __syncthreads();
#pragma unroll
        for (int kk4 = 0; kk4 < 4; kk4++) {
            float4 xv[8];
#pragma unroll
            for (int i = 0; i < 8; i++)
                xv[i] = *reinterpret_cast<const float4*>(&xs[rg * 8 + i][kk4 * 4]);
#pragma unroll
            for (int kq = 0; kq < 4; kq++) {
                float4 wa = *reinterpret_cast<const float4*>(&wsm[kk4 * 4 + kq][lane * 4]);
                float4 wb = *reinterpret_cast<const float4*>(&wsm[kk4 * 4 + kq][256 + lane * 4]);
#pragma unroll
                for (int i = 0; i < 8; i++) {
                    float x = (kq == 0) ? xv[i].x : (kq == 1) ? xv[i].y
                              : (kq == 2) ? xv[i].z : xv[i].w;
                    acc[i][0] += x * wa.x; acc[i][1] += x * wa.y;
                    acc[i][2] += x * wa.z; acc[i][3] += x * wa.w;
                    acc[i][4] += x * wb.x; acc[i][5] += x * wb.y;
                    acc[i][6] += x * wb.z; acc[i][7] += x * wb.w;
                }
            }
        }
        __syncthreads();
    }

    float4 b1a = *reinterpret_cast<const float4*>(&b1[lane * 4]);
    float4 b1b = *reinterpret_cast<const float4*>(&b1[256 + lane * 4]);
    float4 w2a = *reinterpret_cast<const float4*>(&W2[lane * 4]);
    float4 w2b = *reinterpret_cast<const float4*>(&W2[256 + lane * 4]);
    const float bias2 = b2[0];
#pragma unroll
    for (int i = 0; i < 8; i++) {
        float vals[8] = {acc[i][0] + b1a.x, acc[i][1] + b1a.y, acc[i][2] + b1a.z,
                         acc[i][3] + b1a.w, acc[i][4] + b1b.x, acc[i][5] + b1b.y,
                         acc[i][6] + b1b.z, acc[i][7] + b1b.w};
        float w2v[8] = {w2a.x, w2a.y, w2a.z, w2a.w, w2b.x, w2b.y, w2b.z, w2b.w};
        float p = 0.f;
#pragma unroll
        for (int j = 0; j < 8; j++) {
            float v = vals[j];
            float g = 0.5f * v * (1.0f + erff(v * 0.70710678118654752f));
            p += g * w2v[j];
        }
#pragma unroll
        for (int off = 32; off; off >>= 1) p += __shfl_xor(p, off, 64);
        if (lane == 0) logits[rowBase + rg * 8 + i] = p + bias2;
    }
}

// ---------------------------------------------------------------------------
// K2: sigmoid/mask/forced-last, block scan of hard. Emits masked_probs +
// scalars (fp32 out), boundary positions bpos, per-position segment id.
// ---------------------------------------------------------------------------
__global__ __launch_bounds__(1024)
void k_bound(const float* __restrict__ logits, const float* __restrict__ lengths,
             float* __restrict__ out, int S,
             int* __restrict__ nseg, int* __restrict__ bpos,
             int* __restrict__ segid) {
    const int b   = blockIdx.x;
    const int tid = threadIdx.x;          // 1024 threads, 4 t each
    const float alenf = lengths[b] * (float)LL;
    const int alen = (int)alenf;          // truncation, matches .astype(int32)
    int last = alen - 1;
    if (last < 0) last = 0;
    if (last > LL - 1) last = LL - 1;

    float* out_mp = out + (size_t)BB * S * DD;

    int h[4];
    float4 mp_pack;
    float* mpp = reinterpret_cast<float*>(&mp_pack);
#pragma unroll
    for (int i = 0; i < 4; i++) {
        int t = tid * 4 + i;
        float lg = logits[b * LL + t];
        float prob = 1.0f / (1.0f + expf(-lg));
        bool valid = t < alen;
        mpp[i] = valid ? prob : 0.0f;
        int hd = (prob > 0.5f && valid) ? 1 : 0;
        if (t == last) hd = 1;
        h[i] = hd;
    }
    *reinterpret_cast<float4*>(&out_mp[b * LL + tid * 4]) = mp_pack;

    int s4 = h[0] + h[1] + h[2] + h[3];
    const int lane = tid & 63;
    const int wave = tid >> 6;            // 0..15
    int incl = s4;
#pragma unroll
    for (int off = 1; off < 64; off <<= 1) {
        int v = __shfl_up(incl, off, 64);
        if (lane >= off) incl += v;
    }
    __shared__ int wsum[16];
    __shared__ int woff[17];
    if (lane == 63) wsum[wave] = incl;
    __syncthreads();
    if (tid == 0) {
        int r = 0;
        for (int w = 0; w < 16; w++) { woff[w] = r; r += wsum[w]; }
        woff[16] = r;
    }
    __syncthreads();
    int ex = woff[wave] + incl - s4;      // exclusive prefix at this thread's 1st elem
    int4 sg_pack;
    int* sgp = reinterpret_cast<int*>(&sg_pack);
#pragma unroll
    for (int i = 0; i < 4; i++) {
        int t = tid * 4 + i;
        sgp[i] = ex;                      // segment id = #boundaries strictly before t
        if (h[i]) { bpos[b * LL + ex] = t; ex++; }
    }
    *reinterpret_cast<int4*>(&segid[b * LL + tid * 4]) = sg_pack;

    if (tid == 0) {
        int total = woff[16];
        nseg[b] = total;
        float* out_sl = out + (size_t)BB * S * DD + (size_t)BB * LL;
        float* out_nb = out_sl + BB;
        out_nb[b] = (float)total;
        int denom = (S > 1) ? S : 1;
        out_sl[b] = (float)total / (float)denom;
    }
}

// ---------------------------------------------------------------------------
// K3: chunked segmented mean-pool. One wave per CH consecutive positions;
// every hidden row read exactly once -> perfectly balanced.
// Complete segments: plain store; chunk-straddling segments: atomicAdd of
// pre-divided partials (global cnt from bpos). pooled pre-zeroed by memset.
// ---------------------------------------------------------------------------
__global__ __launch_bounds__(256)
void k_pool2(const float* __restrict__ hidden, const int* __restrict__ nseg,
             const int* __restrict__ bpos, const int* __restrict__ segid,
             float* __restrict__ pooled, int S) {
    const int wave = threadIdx.x >> 6;
    const int lane = threadIdx.x & 63;
    const int g  = blockIdx.x * 4 + wave;      // 0 .. B*(LL/CH)-1
    const int b  = g / (LL / CH);
    const int c  = g % (LL / CH);
    const int t0 = c * CH;
    const int n  = nseg[b];
    const int* sgid = segid + b * LL;
    const int* bp   = bpos + b * LL;
    const float* hb = hidden + (size_t)b * LL * DD;
    float* pb = pooled + (size_t)b * S * DD;

    float4 a0 = {0.f, 0.f, 0.f, 0.f};
    float4 a1 = {0.f, 0.f, 0.f, 0.f};
    int cur = -1;          // active segment id (-1 = none)
    int cur_start = 0;     // segment's TRUE global start

    for (int t = t0; t < t0 + CH; t++) {
        int sg = sgid[t];
        if (sg != cur) {
            if (cur >= 0) {
                // flush segment `cur`; its last accumulated position is t-1
                int real_end = (cur < n) ? bp[cur] : (LL - 1);
                float inv = 1.0f / (float)(real_end - cur_start + 1);
                float* dst = pb + (size_t)cur * DD;
                bool complete = (cur_start >= t0) && (t - 1 == real_end);
                if (complete) {
                    float4 r0 = {a0.x * inv, a0.y * inv, a0.z * inv, a0.w * inv};
                    float4 r1 = {a1.x * inv, a1.y * inv, a1.z * inv, a1.w * inv};
                    *reinterpret_cast<float4*>(&dst[lane * 4]) = r0;
                    *reinterpret_cast<float4*>(&dst[256 + lane * 4]) = r1;
                } else {
                    atomicAdd(&dst[lane * 4 + 0], a0.x * inv);
                    atomicAdd(&dst[lane * 4 + 1], a0.y * inv);
                    atomicAdd(&dst[lane * 4 + 2], a0.z * inv);
                    atomicAdd(&dst[lane * 4 + 3], a0.w * inv);
                    atomicAdd(&dst[256 + lane * 4 + 0], a1.x * inv);
                    atomicAdd(&dst[256 + lane * 4 + 1], a1.y * inv);
                    atomicAdd(&dst[256 + lane * 4 + 2], a1.z * inv);
                    atomicAdd(&dst[256 + lane * 4 + 3], a1.w * inv);
                }
            }
            if (sg < S) {
                cur = sg;
                cur_start = (sg > 0) ? bp[sg - 1] + 1 : 0;
                a0 = {0.f, 0.f, 0.f, 0.f};
                a1 = {0.f, 0.f, 0.f, 0.f};
            } else {
                cur = -1;
            }
        }
        if (cur >= 0) {
            float4 v0 = *reinterpret_cast<const float4*>(&hb[(size_t)t * DD + lane * 4]);
            float4 v1 = *reinterpret_cast<const float4*>(&hb[(size_t)t * DD + 256 + lane * 4]);
            a0.x += v0.x; a0.y += v0.y; a0.z += v0.z; a0.w += v0.w;
            a1.x += v1.x; a1.y += v1.y; a1.z += v1.z; a1.w += v1.w;
        }
    }
    if (cur >= 0) {        // final flush at chunk end (last position = t0+CH-1)
        int real_end = (cur < n) ? bp[cur] : (LL - 1);
        float inv = 1.0f / (float)(real_end - cur_start + 1);
        float* dst = pb + (size_t)cur * DD;
        bool complete = (cur_start >= t0) && (t0 + CH - 1 == real_end);
        if (complete) {
            float4 r0 = {a0.x * inv, a0.y * inv, a0.z * inv, a0.w * inv};
            float4 r1 = {a1.x * inv, a1.y * inv, a1.z * inv, a1.w * inv};
            *reinterpret_cast<float4*>(&dst[lane * 4]) = r0;
            *reinterpret_cast<float4*>(&dst[256 + lane * 4]) = r1;
        } else {
            atomicAdd(&dst[lane * 4 + 0], a0.x * inv);
            atomicAdd(&dst[lane * 4 + 1], a0.y * inv);
            atomicAdd(&dst[lane * 4 + 2], a0.z * inv);
            atomicAdd(&dst[lane * 4 + 3], a0.w * inv);
            atomicAdd(&dst[256 + lane * 4 + 0], a1.x * inv);
            atomicAdd(&dst[256 + lane * 4 + 1], a1.y * inv);
            atomicAdd(&dst[256 + lane * 4 + 2], a1.z * inv);
            atomicAdd(&dst[256 + lane * 4 + 3], a1.w * inv);
        }
    }
}

// ---------------------------------------------------------------------------
extern "C" void kernel_launch(void* const* d_in, const int* in_sizes, int n_in,
                              void* d_out, int out_size, void* d_ws, size_t ws_size,
                              hipStream_t stream) {
    const float* hidden  = (const float*)d_in[0];
    const float* lengths = (const float*)d_in[1];
    const float* W1      = (const float*)d_in[2];
    const float* b1      = (const float*)d_in[3];
    const float* W2      = (const float*)d_in[4];
    const float* b2      = (const float*)d_in[5];
    float* out           = (float*)d_out;

    const int S = (out_size - BB * LL - 2 * BB) / (BB * DD);

    float* logits = (float*)d_ws;                                    // B*L f32
    int*   bpos   = (int*)((char*)d_ws + (size_t)BB * LL * 4);       // B*L i32
    int*   segid  = (int*)((char*)d_ws + (size_t)2 * BB * LL * 4);   // B*L i32
    int*   nseg   = (int*)((char*)d_ws + (size_t)3 * BB * LL * 4);   // B i32

    // zero the pooled region (atomic targets + s>n segments)
    hipMemsetAsync(out, 0, (size_t)BB * S * DD * sizeof(float), stream);

    k_logits<<<(BB * LL) / 64, 512, 0, stream>>>(hidden, W1, b1, W2, b2, logits);
    k_bound<<<BB, 1024, 0, stream>>>(logits, lengths, out, S, nseg, bpos, segid);
    k_pool2<<<(BB * (LL / CH)) / 4, 256, 0, stream>>>(hidden, nseg, bpos, segid, out, S);
}

// Round 4
// 276.518 us; speedup vs baseline: 4.8858x; 1.2985x over previous
//
#include <hip/hip_runtime.h>
#include <hip/hip_bf16.h>
#include <math.h>

#define BB 8
#define LL 4096
#define DD 512
#define CH 32            // positions per pooling chunk (one wave each)

typedef __attribute__((ext_vector_type(8))) short bfx8;
typedef __attribute__((ext_vector_type(4))) float fx4;

static __device__ __forceinline__ unsigned short bf_hi(float x) {
    __hip_bfloat16 h = __float2bfloat16(x);
    return *reinterpret_cast<unsigned short*>(&h);
}
static __device__ __forceinline__ float bf_f(unsigned short u) {
    __hip_bfloat16 h = *reinterpret_cast<__hip_bfloat16*>(&u);
    return __bfloat162float(h);
}

// ---------------------------------------------------------------------------
// K0: split W1 (fp32 [K=512][N=512]) into transposed bf16 planes
// Wt_hi/Wt_lo [N][K].  One thread per 8-k chunk of one output row.
// ---------------------------------------------------------------------------
__global__ __launch_bounds__(256)
void k_split(const float* __restrict__ W1, unsigned short* __restrict__ wt_hi,
             unsigned short* __restrict__ wt_lo) {
    int g = blockIdx.x * 256 + threadIdx.x;      // 0 .. 32767
    int n  = g >> 6;                             // output row (W1 col)
    int kc = g & 63;                             // 8-k chunk
    ushort4 h0, h1, l0, l1;
    unsigned short* hp = reinterpret_cast<unsigned short*>(&h0);
    unsigned short* lp = reinterpret_cast<unsigned short*>(&l0);
#pragma unroll
    for (int j = 0; j < 8; j++) {
        float x = W1[(size_t)(kc * 8 + j) * DD + n];
        unsigned short hi = bf_hi(x);
        unsigned short lo = bf_hi(x - bf_f(hi));
        if (j < 4) { hp[j] = hi; lp[j] = lo; }
        else { reinterpret_cast<unsigned short*>(&h1)[j-4] = hi;
               reinterpret_cast<unsigned short*>(&l1)[j-4] = lo; }
    }
    size_t off = (size_t)n * DD + kc * 8;
    *reinterpret_cast<ushort4*>(&wt_hi[off])     = h0;
    *reinterpret_cast<ushort4*>(&wt_hi[off + 4]) = h1;
    *reinterpret_cast<ushort4*>(&wt_lo[off])     = l0;
    *reinterpret_cast<ushort4*>(&wt_lo[off + 4]) = l1;
}

// ---------------------------------------------------------------------------
// K1: split-bf16 MFMA GEMM + fused GELU + W2 GEMV partials -> atomicAdd logits
// 128x128 tile, BK=64, 4 waves (64x64 each, 4x4 frags of 16x16x32).
// 3 MFMA products per frag-pair: hi*hi + hi*lo + lo*hi.
// LDS planes [128][64] bf16, XOR-swizzled (byte ^= (row&7)<<4).
// ---------------------------------------------------------------------------
__global__ __launch_bounds__(256, 2)
void k_mfma(const float* __restrict__ hidden,
            const unsigned short* __restrict__ wt_hi,
            const unsigned short* __restrict__ wt_lo,
            const float* __restrict__ b1, const float* __restrict__ W2,
            float* __restrict__ logits) {
    __shared__ __align__(16) char lds[65536];   // A_hi A_lo B_hi B_lo, 16KB each
    const int tid  = threadIdx.x;
    const int wave = tid >> 6;
    const int lane = tid & 63;
    const int grp  = lane >> 4;
    const int lid  = lane & 15;
    const int wr   = wave >> 1;     // row half
    const int wc   = wave & 1;      // col half

    // XCD-aware swizzle (1024 blocks, 8 XCDs): contiguous wg chunk per XCD
    int wg = (blockIdx.x & 7) * 128 + (blockIdx.x >> 3);
    const int colTile = wg & 3;
    const int rowTile = wg >> 2;
    const int rowBase = rowTile * 128;
    const int colBase = colTile * 128;

    fx4 acc[4][4];
#pragma unroll
    for (int m = 0; m < 4; m++)
#pragma unroll
        for (int n = 0; n < 4; n++) acc[m][n] = {0.f, 0.f, 0.f, 0.f};

    float4 av[8];
    uint4  bv[8];

    // staging coordinates (fixed per thread)
    // A: idx = tid + i*256 -> row = idx>>4, kq = idx&15 (4 f32 each)
    // B: idx = tid + i*256 -> plane = idx>=1024, pidx=idx&1023, col=pidx>>3, kc=pidx&7
#define LOAD_A(kt)  {                                                          \
    _Pragma("unroll")                                                          \
    for (int i = 0; i < 8; i++) {                                              \
        int idx = tid + i * 256; int row = idx >> 4; int kq = idx & 15;        \
        av[i] = *reinterpret_cast<const float4*>(                              \
            &hidden[(size_t)(rowBase + row) * DD + (kt) * 64 + kq * 4]); } }
#define LOAD_B(kt)  {                                                          \
    _Pragma("unroll")                                                          \
    for (int i = 0; i < 8; i++) {                                              \
        int idx = tid + i * 256; int pidx = idx & 1023;                        \
        int col = pidx >> 3; int kc = pidx & 7;                                \
        const unsigned short* src = (idx < 1024 ? wt_hi : wt_lo);              \
        bv[i] = *reinterpret_cast<const uint4*>(                               \
            &src[(size_t)(colBase + col) * DD + (kt) * 64 + kc * 8]); } }

    LOAD_A(0); LOAD_B(0);

    for (int kt = 0; kt < 8; kt++) {
        __syncthreads();               // previous compute done, LDS free
#pragma unroll
        for (int i = 0; i < 8; i++) {  // A: split fp32 -> hi/lo, swizzled write
            int idx = tid + i * 256; int row = idx >> 4; int kq = idx & 15;
            ushort4 hi4, lo4;
            unsigned short* hp = reinterpret_cast<unsigned short*>(&hi4);
            unsigned short* lp = reinterpret_cast<unsigned short*>(&lo4);
            float xv[4] = {av[i].x, av[i].y, av[i].z, av[i].w};
#pragma unroll
            for (int e = 0; e < 4; e++) {
                unsigned short h = bf_hi(xv[e]);
                hp[e] = h; lp[e] = bf_hi(xv[e] - bf_f(h));
            }
            int aoff = row * 128 + ((kq * 8) ^ ((row & 7) << 4));
            *reinterpret_cast<ushort4*>(lds + aoff)         = hi4;
            *reinterpret_cast<ushort4*>(lds + 16384 + aoff) = lo4;
        }
#pragma unroll
        for (int i = 0; i < 8; i++) {  // B: swizzled write
            int idx = tid + i * 256; int pidx = idx & 1023;
            int col = pidx >> 3; int kc = pidx & 7;
            int boff = col * 128 + ((kc * 16) ^ ((col & 7) << 4));
            int base = (idx < 1024) ? 32768 : 49152;
            *reinterpret_cast<uint4*>(lds + base + boff) = bv[i];
        }
        __syncthreads();
        if (kt < 7) { LOAD_A(kt + 1); LOAD_B(kt + 1); }  // hide HBM under MFMA

#pragma unroll
        for (int ks = 0; ks < 2; ks++) {
            bfx8 ah[4], al[4], bh[4], bl[4];
            const int kb = ks * 64 + grp * 16;
#pragma unroll
            for (int m = 0; m < 4; m++) {
                int arow = wr * 64 + m * 16 + lid;
                int off = arow * 128 + (kb ^ ((arow & 7) << 4));
                ah[m] = *reinterpret_cast<const bfx8*>(lds + off);
                al[m] = *reinterpret_cast<const bfx8*>(lds + 16384 + off);
            }
#pragma unroll
            for (int n = 0; n < 4; n++) {
                int bcol = wc * 64 + n * 16 + lid;
                int off = bcol * 128 + (kb ^ ((bcol & 7) << 4));
                bh[n] = *reinterpret_cast<const bfx8*>(lds + 32768 + off);
                bl[n] = *reinterpret_cast<const bfx8*>(lds + 49152 + off);
            }
#pragma unroll
            for (int m = 0; m < 4; m++)
#pragma unroll
                for (int n = 0; n < 4; n++) {
                    acc[m][n] = __builtin_amdgcn_mfma_f32_16x16x32_bf16(
                        ah[m], bh[n], acc[m][n], 0, 0, 0);
                    acc[m][n] = __builtin_amdgcn_mfma_f32_16x16x32_bf16(
                        ah[m], bl[n], acc[m][n], 0, 0, 0);
                    acc[m][n] = __builtin_amdgcn_mfma_f32_16x16x32_bf16(
                        al[m], bh[n], acc[m][n], 0, 0, 0);
                }
        }
    }

    // epilogue: +b1, exact-erf gelu, * W2, 16-lane butterfly, atomicAdd logits
    float w2v[4], b1v[4];
#pragma unroll
    for (int n = 0; n < 4; n++) {
        int c = colBase + wc * 64 + n * 16 + lid;
        w2v[n] = W2[c]; b1v[n] = b1[c];
    }
#pragma unroll
    for (int m = 0; m < 4; m++)
#pragma unroll
        for (int reg = 0; reg < 4; reg++) {
            float p = 0.f;
#pragma unroll
            for (int n = 0; n < 4; n++) {
                float v = acc[m][n][reg] + b1v[n];
                float g = 0.5f * v * (1.0f + erff(v * 0.70710678118654752f));
                p += g * w2v[n];
            }
            p += __shfl_xor(p, 1, 64);
            p += __shfl_xor(p, 2, 64);
            p += __shfl_xor(p, 4, 64);
            p += __shfl_xor(p, 8, 64);
            if (lid == 0)
                atomicAdd(&logits[rowBase + wr * 64 + m * 16 + grp * 4 + reg], p);
        }
}

// ---------------------------------------------------------------------------
// K2: sigmoid/mask/forced-last (+b2 here: logits hold pre-bias partial sums),
// block scan of hard -> masked_probs, scalars, bpos, segid.
// ---------------------------------------------------------------------------
__global__ __launch_bounds__(1024)
void k_bound(const float* __restrict__ logits, const float* __restrict__ lengths,
             const float* __restrict__ b2, float* __restrict__ out, int S,
             int* __restrict__ nseg, int* __restrict__ bpos,
             int* __restrict__ segid) {
    const int b   = blockIdx.x;
    const int tid = threadIdx.x;          // 1024 threads, 4 t each
    const float alenf = lengths[b] * (float)LL;
    const int alen = (int)alenf;          // truncation, matches .astype(int32)
    const float b2v = b2[0];
    int last = alen - 1;
    if (last < 0) last = 0;
    if (last > LL - 1) last = LL - 1;

    float* out_mp = out + (size_t)BB * S * DD;

    int h[4];
    float4 mp_pack;
    float* mpp = reinterpret_cast<float*>(&mp_pack);
#pragma unroll
    for (int i = 0; i < 4; i++) {
        int t = tid * 4 + i;
        float lg = logits[b * LL + t] + b2v;
        float prob = 1.0f / (1.0f + expf(-lg));
        bool valid = t < alen;
        mpp[i] = valid ? prob : 0.0f;
        int hd = (prob > 0.5f && valid) ? 1 : 0;
        if (t == last) hd = 1;
        h[i] = hd;
    }
    *reinterpret_cast<float4*>(&out_mp[b * LL + tid * 4]) = mp_pack;

    int s4 = h[0] + h[1] + h[2] + h[3];
    const int lane = tid & 63;
    const int wave = tid >> 6;            // 0..15
    int incl = s4;
#pragma unroll
    for (int off = 1; off < 64; off <<= 1) {
        int v = __shfl_up(incl, off, 64);
        if (lane >= off) incl += v;
    }
    __shared__ int wsum[16];
    __shared__ int woff[17];
    if (lane == 63) wsum[wave] = incl;
    __syncthreads();
    if (tid == 0) {
        int r = 0;
        for (int w = 0; w < 16; w++) { woff[w] = r; r += wsum[w]; }
        woff[16] = r;
    }
    __syncthreads();
    int ex = woff[wave] + incl - s4;      // exclusive prefix at this thread's 1st elem
    int4 sg_pack;
    int* sgp = reinterpret_cast<int*>(&sg_pack);
#pragma unroll
    for (int i = 0; i < 4; i++) {
        int t = tid * 4 + i;
        sgp[i] = ex;                      // segment id = #boundaries strictly before t
        if (h[i]) { bpos[b * LL + ex] = t; ex++; }
    }
    *reinterpret_cast<int4*>(&segid[b * LL + tid * 4]) = sg_pack;

    if (tid == 0) {
        int total = woff[16];
        nseg[b] = total;
        float* out_sl = out + (size_t)BB * S * DD + (size_t)BB * LL;
        float* out_nb = out_sl + BB;
        out_nb[b] = (float)total;
        int denom = (S > 1) ? S : 1;
        out_sl[b] = (float)total / (float)denom;
    }
}

// ---------------------------------------------------------------------------
// K3: chunked segmented mean-pool (balanced; atomics only at chunk edges).
// ---------------------------------------------------------------------------
__global__ __launch_bounds__(256)
void k_pool2(const float* __restrict__ hidden, const int* __restrict__ nseg,
             const int* __restrict__ bpos, const int* __restrict__ segid,
             float* __restrict__ pooled, int S) {
    const int wave = threadIdx.x >> 6;
    const int lane = threadIdx.x & 63;
    const int g  = blockIdx.x * 4 + wave;      // 0 .. B*(LL/CH)-1
    const int b  = g / (LL / CH);
    const int c  = g % (LL / CH);
    const int t0 = c * CH;
    const int n  = nseg[b];
    const int* sgid = segid + b * LL;
    const int* bp   = bpos + b * LL;
    const float* hb = hidden + (size_t)b * LL * DD;
    float* pb = pooled + (size_t)b * S * DD;

    float4 a0 = {0.f, 0.f, 0.f, 0.f};
    float4 a1 = {0.f, 0.f, 0.f, 0.f};
    int cur = -1;
    int cur_start = 0;

    for (int t = t0; t < t0 + CH; t++) {
        int sg = sgid[t];
        if (sg != cur) {
            if (cur >= 0) {
                int real_end = (cur < n) ? bp[cur] : (LL - 1);
                float inv = 1.0f / (float)(real_end - cur_start + 1);
                float* dst = pb + (size_t)cur * DD;
                bool complete = (cur_start >= t0) && (t - 1 == real_end);
                if (complete) {
                    float4 r0 = {a0.x * inv, a0.y * inv, a0.z * inv, a0.w * inv};
                    float4 r1 = {a1.x * inv, a1.y * inv, a1.z * inv, a1.w * inv};
                    *reinterpret_cast<float4*>(&dst[lane * 4]) = r0;
                    *reinterpret_cast<float4*>(&dst[256 + lane * 4]) = r1;
                } else {
                    atomicAdd(&dst[lane * 4 + 0], a0.x * inv);
                    atomicAdd(&dst[lane * 4 + 1], a0.y * inv);
                    atomicAdd(&dst[lane * 4 + 2], a0.z * inv);
                    atomicAdd(&dst[lane * 4 + 3], a0.w * inv);
                    atomicAdd(&dst[256 + lane * 4 + 0], a1.x * inv);
                    atomicAdd(&dst[256 + lane * 4 + 1], a1.y * inv);
                    atomicAdd(&dst[256 + lane * 4 + 2], a1.z * inv);
                    atomicAdd(&dst[256 + lane * 4 + 3], a1.w * inv);
                }
            }
            if (sg < S) {
                cur = sg;
                cur_start = (sg > 0) ? bp[sg - 1] + 1 : 0;
                a0 = {0.f, 0.f, 0.f, 0.f};
                a1 = {0.f, 0.f, 0.f, 0.f};
            } else {
                cur = -1;
            }
        }
        if (cur >= 0) {
            float4 v0 = *reinterpret_cast<const float4*>(&hb[(size_t)t * DD + lane * 4]);
            float4 v1 = *reinterpret_cast<const float4*>(&hb[(size_t)t * DD + 256 + lane * 4]);
            a0.x += v0.x; a0.y += v0.y; a0.z += v0.z; a0.w += v0.w;
            a1.x += v1.x; a1.y += v1.y; a1.z += v1.z; a1.w += v1.w;
        }
    }
    if (cur >= 0) {
        int real_end = (cur < n) ? bp[cur] : (LL - 1);
        float inv = 1.0f / (float)(real_end - cur_start + 1);
        float* dst = pb + (size_t)cur * DD;
        bool complete = (cur_start >= t0) && (t0 + CH - 1 == real_end);
        if (complete) {
            float4 r0 = {a0.x * inv, a0.y * inv, a0.z * inv, a0.w * inv};
            float4 r1 = {a1.x * inv, a1.y * inv, a1.z * inv, a1.w * inv};
            *reinterpret_cast<float4*>(&dst[lane * 4]) = r0;
            *reinterpret_cast<float4*>(&dst[256 + lane * 4]) = r1;
        } else {
            atomicAdd(&dst[lane * 4 + 0], a0.x * inv);
            atomicAdd(&dst[lane * 4 + 1], a0.y * inv);
            atomicAdd(&dst[lane * 4 + 2], a0.z * inv);
            atomicAdd(&dst[lane * 4 + 3], a0.w * inv);
            atomicAdd(&dst[256 + lane * 4 + 0], a1.x * inv);
            atomicAdd(&dst[256 + lane * 4 + 1], a1.y * inv);
            atomicAdd(&dst[256 + lane * 4 + 2], a1.z * inv);
            atomicAdd(&dst[256 + lane * 4 + 3], a1.w * inv);
        }
    }
}

// ---------------------------------------------------------------------------
extern "C" void kernel_launch(void* const* d_in, const int* in_sizes, int n_in,
                              void* d_out, int out_size, void* d_ws, size_t ws_size,
                              hipStream_t stream) {
    const float* hidden  = (const float*)d_in[0];
    const float* lengths = (const float*)d_in[1];
    const float* W1      = (const float*)d_in[2];
    const float* b1      = (const float*)d_in[3];
    const float* W2      = (const float*)d_in[4];
    const float* b2      = (const float*)d_in[5];
    float* out           = (float*)d_out;

    const int S = (out_size - BB * LL - 2 * BB) / (BB * DD);

    float* logits = (float*)d_ws;                                     // B*L f32
    int*   bpos   = (int*)((char*)d_ws + (size_t)BB * LL * 4);        // B*L i32
    int*   segid  = (int*)((char*)d_ws + (size_t)2 * BB * LL * 4);    // B*L i32
    int*   nseg   = (int*)((char*)d_ws + (size_t)3 * BB * LL * 4);    // B i32
    unsigned short* wt_hi = (unsigned short*)((char*)d_ws + (size_t)3 * BB * LL * 4 + 1024);
    unsigned short* wt_lo = wt_hi + (size_t)DD * DD;

    hipMemsetAsync(out, 0, (size_t)BB * S * DD * sizeof(float), stream);
    hipMemsetAsync(logits, 0, (size_t)BB * LL * sizeof(float), stream);

    k_split<<<128, 256, 0, stream>>>(W1, wt_hi, wt_lo);
    k_mfma<<<1024, 256, 0, stream>>>(hidden, wt_hi, wt_lo, b1, W2, logits);
    k_bound<<<BB, 1024, 0, stream>>>(logits, lengths, b2, out, S, nseg, bpos, segid);
    k_pool2<<<(BB * (LL / CH)) / 4, 256, 0, stream>>>(hidden, nseg, bpos, segid, out, S);
}

// Round 6
// 202.455 us; speedup vs baseline: 6.6732x; 1.3658x over previous
//
#include <hip/hip_runtime.h>
#include <hip/hip_bf16.h>
#include <math.h>

#define BB 8
#define LL 4096
#define DD 512
#define CH 32            // positions per pooling chunk (one wave each)

typedef __attribute__((ext_vector_type(8))) short bfx8;
typedef __attribute__((ext_vector_type(8))) unsigned short usx8;
typedef __attribute__((ext_vector_type(4))) float fx4;

static __device__ __forceinline__ unsigned short bf_hi(float x) {
    __hip_bfloat16 h = __float2bfloat16(x);
    return *reinterpret_cast<unsigned short*>(&h);
}
static __device__ __forceinline__ float bf_f(unsigned short u) {
    __hip_bfloat16 h = *reinterpret_cast<__hip_bfloat16*>(&u);
    return __bfloat162float(h);
}
static __device__ __forceinline__ void glds16(const void* g, void* l) {
    __builtin_amdgcn_global_load_lds(
        (const __attribute__((address_space(1))) unsigned int*)g,
        (__attribute__((address_space(3))) unsigned int*)l, 16, 0, 0);
}

// ---------------------------------------------------------------------------
// K0: split W1 (fp32 [K=512][N=512]) into transposed bf16 planes
// Wt_hi/Wt_lo [N][K].
// ---------------------------------------------------------------------------
__global__ __launch_bounds__(256)
void k_split(const float* __restrict__ W1, unsigned short* __restrict__ wt_hi,
             unsigned short* __restrict__ wt_lo) {
    int g = blockIdx.x * 256 + threadIdx.x;      // 0 .. 32767
    int n  = g >> 6;                             // output row (W1 col)
    int kc = g & 63;                             // 8-k chunk
    ushort4 h0, h1, l0, l1;
    unsigned short* hp = reinterpret_cast<unsigned short*>(&h0);
    unsigned short* lp = reinterpret_cast<unsigned short*>(&l0);
#pragma unroll
    for (int j = 0; j < 8; j++) {
        float x = W1[(size_t)(kc * 8 + j) * DD + n];
        unsigned short hi = bf_hi(x);
        unsigned short lo = bf_hi(x - bf_f(hi));
        if (j < 4) { hp[j] = hi; lp[j] = lo; }
        else { reinterpret_cast<unsigned short*>(&h1)[j-4] = hi;
               reinterpret_cast<unsigned short*>(&l1)[j-4] = lo; }
    }
    size_t off = (size_t)n * DD + kc * 8;
    *reinterpret_cast<ushort4*>(&wt_hi[off])     = h0;
    *reinterpret_cast<ushort4*>(&wt_hi[off + 4]) = h1;
    *reinterpret_cast<ushort4*>(&wt_lo[off])     = l0;
    *reinterpret_cast<ushort4*>(&wt_lo[off + 4]) = l1;
}

// ---------------------------------------------------------------------------
// K1: split-bf16 MFMA GEMM + fused GELU + W2 GEMV -> logits partials
// 128x128 tile, BK=64, 512 threads / 8 waves (2Mx4N), 64x32 per wave,
// frags 4m x 2n of 16x16x32. 3 MFMA products: hi*hi + hi*lo + lo*hi.
// A: reg-staged fp32->split->ds_write, XOR-swizzled (byte ^= (row&7)<<4).
// B: global_load_lds, linear LDS dest + pre-swizzled per-lane source.
// NOTE: 4 colTile wgs contribute to the same logits rows -> atomicAdd
// (round-5 bug: plain store raced across colTiles).
// ---------------------------------------------------------------------------
__global__ __launch_bounds__(512, 4)
void k_mfma(const float* __restrict__ hidden,
            const unsigned short* __restrict__ wt_hi,
            const unsigned short* __restrict__ wt_lo,
            const float* __restrict__ b1, const float* __restrict__ W2,
            float* __restrict__ logits) {
    __shared__ __align__(16) char lds[65536];   // A_hi A_lo B_hi B_lo, 16KB each
    const int tid  = threadIdx.x;
    const int wave = tid >> 6;
    const int lane = tid & 63;
    const int grp  = lane >> 4;
    const int lid  = lane & 15;
    const int wr   = wave >> 2;     // 0..1  (64-row half)
    const int wc   = wave & 3;      // 0..3  (32-col quarter)

    // XCD-aware swizzle: 1024 wgs, 8 XCDs -> contiguous 128-wg chunk per XCD;
    // consecutive wg share rowTile (A-panel L2 reuse), B (512KB) fits XCD L2.
    int wg = (blockIdx.x & 7) * 128 + (blockIdx.x >> 3);
    const int colTile = wg & 3;
    const int rowTile = wg >> 2;
    const int rowBase = rowTile * 128;
    const int colBase = colTile * 128;

    fx4 acc[4][2];
#pragma unroll
    for (int m = 0; m < 4; m++)
#pragma unroll
        for (int n = 0; n < 2; n++) acc[m][n] = {0.f, 0.f, 0.f, 0.f};

    // ---- A staging coords: thread t -> row t>>2, 16-float quarter t&3
    const int arow = tid >> 2;
    const int aq   = tid & 3;
    const float* aSrc = hidden + (size_t)(rowBase + arow) * DD + aq * 16;

    // ---- B global_load_lds coords: 32 instrs (8 waves x 4), 1KB each.
    // gi -> plane (hi/lo), 8-col group. LDS dest linear (lane*16B);
    // source chunk pre-swizzled: chunk = (l&7)^(l>>3) so swizzled read works.
    const unsigned short* bsrc[4];
    char* bdst[4];
#pragma unroll
    for (int i = 0; i < 4; i++) {
        int gi = wave * 4 + i;               // 0..31
        int plane = gi >> 4;                 // 0=hi 1=lo
        int pi = gi & 15;                    // 8-col group
        int col = pi * 8 + (lane >> 3);
        int chunk = (lane & 7) ^ (lane >> 3);
        const unsigned short* srcp = plane ? wt_lo : wt_hi;
        bsrc[i] = srcp + (size_t)(colBase + col) * DD + chunk * 8;
        bdst[i] = lds + 32768 + plane * 16384 + pi * 1024;
    }

    float4 av[4];
#pragma unroll
    for (int j = 0; j < 4; j++) av[j] = *reinterpret_cast<const float4*>(aSrc + j * 4);

    for (int kt = 0; kt < 8; kt++) {
        __syncthreads();   // prev MFMA done reading LDS; also drains av loads

        // A: split fp32 -> hi/lo bf16, swizzled ds_write (2x b128 per plane)
#pragma unroll
        for (int j = 0; j < 2; j++) {
            usx8 hi8, lo8;
            float xv[8] = {av[2*j].x, av[2*j].y, av[2*j].z, av[2*j].w,
                           av[2*j+1].x, av[2*j+1].y, av[2*j+1].z, av[2*j+1].w};
#pragma unroll
            for (int e = 0; e < 8; e++) {
                unsigned short h = bf_hi(xv[e]);
                hi8[e] = (short)h;
                lo8[e] = (short)bf_hi(xv[e] - bf_f(h));
            }
            int aoff = arow * 128 + ((aq * 32 + j * 16) ^ ((arow & 7) << 4));
            *reinterpret_cast<usx8*>(lds + aoff)         = hi8;
            *reinterpret_cast<usx8*>(lds + 16384 + aoff) = lo8;
        }
        // B: async global->LDS (this kt)
#pragma unroll
        for (int i = 0; i < 4; i++) glds16(bsrc[i] + kt * 64, bdst[i]);

        __syncthreads();   // drains A ds_writes + B global_load_lds

        if (kt < 7) {      // prefetch next A tile (av dead after split above)
#pragma unroll
            for (int j = 0; j < 4; j++)
                av[j] = *reinterpret_cast<const float4*>(aSrc + (kt + 1) * 64 + j * 4);
        }

        // MFMA phase
#pragma unroll
        for (int ks = 0; ks < 2; ks++) {
            const int kb = ks * 64 + grp * 16;            // byte offset in row
            const int sw = kb ^ ((lid & 7) << 4);
            bfx8 ah[4], bh[2], bl[2], al[4];
#pragma unroll
            for (int m = 0; m < 4; m++) {
                int off = (wr * 64 + m * 16 + lid) * 128 + sw;
                ah[m] = *reinterpret_cast<const bfx8*>(lds + off);
            }
#pragma unroll
            for (int n = 0; n < 2; n++) {
                int off = (wc * 32 + n * 16 + lid) * 128 + sw;
                bh[n] = *reinterpret_cast<const bfx8*>(lds + 32768 + off);
                bl[n] = *reinterpret_cast<const bfx8*>(lds + 49152 + off);
            }
            __builtin_amdgcn_s_setprio(1);
#pragma unroll
            for (int m = 0; m < 4; m++)
#pragma unroll
                for (int n = 0; n < 2; n++)
                    acc[m][n] = __builtin_amdgcn_mfma_f32_16x16x32_bf16(
                        ah[m], bh[n], acc[m][n], 0, 0, 0);
#pragma unroll
            for (int m = 0; m < 4; m++)
#pragma unroll
                for (int n = 0; n < 2; n++)
                    acc[m][n] = __builtin_amdgcn_mfma_f32_16x16x32_bf16(
                        ah[m], bl[n], acc[m][n], 0, 0, 0);
#pragma unroll
            for (int m = 0; m < 4; m++) {
                int off = (wr * 64 + m * 16 + lid) * 128 + sw;
                al[m] = *reinterpret_cast<const bfx8*>(lds + 16384 + off);
            }
#pragma unroll
            for (int m = 0; m < 4; m++)
#pragma unroll
                for (int n = 0; n < 2; n++)
                    acc[m][n] = __builtin_amdgcn_mfma_f32_16x16x32_bf16(
                        al[m], bh[n], acc[m][n], 0, 0, 0);
            __builtin_amdgcn_s_setprio(0);
        }
    }

    // epilogue: +b1, exact-erf gelu, * W2, 16-lane butterfly ->
    // parts[row][wc] in LDS, cross-wave sum, atomicAdd into logits
    // (4 colTile wgs accumulate into the same rows; logits pre-zeroed).
    float w2v[2], b1v[2];
#pragma unroll
    for (int n = 0; n < 2; n++) {
        int c = colBase + wc * 32 + n * 16 + lid;
        w2v[n] = W2[c]; b1v[n] = b1[c];
    }
    __syncthreads();                 // all waves done with LDS frag reads
    float* parts = reinterpret_cast<float*>(lds);   // [128][4]
#pragma unroll
    for (int m = 0; m < 4; m++)
#pragma unroll
        for (int reg = 0; reg < 4; reg++) {
            float p = 0.f;
#pragma unroll
            for (int n = 0; n < 2; n++) {
                float v = acc[m][n][reg] + b1v[n];
                float g = 0.5f * v * (1.0f + erff(v * 0.70710678118654752f));
                p += g * w2v[n];
            }
            p += __shfl_xor(p, 1, 64);
            p += __shfl_xor(p, 2, 64);
            p += __shfl_xor(p, 4, 64);
            p += __shfl_xor(p, 8, 64);
            if (lid == 0)
                parts[(wr * 64 + m * 16 + grp * 4 + reg) * 4 + wc] = p;
        }
    __syncthreads();
    if (tid < 128) {
        float4 v = *reinterpret_cast<const float4*>(parts + tid * 4);
        atomicAdd(&logits[rowBase + tid], v.x + v.y + v.z + v.w);
    }
}

// ---------------------------------------------------------------------------
// K2: sigmoid/mask/forced-last (+b2), block scan of hard -> masked_probs,
// scalars, bpos, segid.
// ---------------------------------------------------------------------------
__global__ __launch_bounds__(1024)
void k_bound(const float* __restrict__ logits, const float* __restrict__ lengths,
             const float* __restrict__ b2, float* __restrict__ out, int S,
             int* __restrict__ nseg, int* __restrict__ bpos,
             int* __restrict__ segid) {
    const int b   = blockIdx.x;
    const int tid = threadIdx.x;          // 1024 threads, 4 t each
    const float alenf = lengths[b] * (float)LL;
    const int alen = (int)alenf;          // truncation, matches .astype(int32)
    const float b2v = b2[0];
    int last = alen - 1;
    if (last < 0) last = 0;
    if (last > LL - 1) last = LL - 1;

    float* out_mp = out + (size_t)BB * S * DD;

    int h[4];
    float4 mp_pack;
    float* mpp = reinterpret_cast<float*>(&mp_pack);
#pragma unroll
    for (int i = 0; i < 4; i++) {
        int t = tid * 4 + i;
        float lg = logits[b * LL + t] + b2v;
        float prob = 1.0f / (1.0f + expf(-lg));
        bool valid = t < alen;
        mpp[i] = valid ? prob : 0.0f;
        int hd = (prob > 0.5f && valid) ? 1 : 0;
        if (t == last) hd = 1;
        h[i] = hd;
    }
    *reinterpret_cast<float4*>(&out_mp[b * LL + tid * 4]) = mp_pack;

    int s4 = h[0] + h[1] + h[2] + h[3];
    const int lane = tid & 63;
    const int wave = tid >> 6;            // 0..15
    int incl = s4;
#pragma unroll
    for (int off = 1; off < 64; off <<= 1) {
        int v = __shfl_up(incl, off, 64);
        if (lane >= off) incl += v;
    }
    __shared__ int wsum[16];
    __shared__ int woff[17];
    if (lane == 63) wsum[wave] = incl;
    __syncthreads();
    if (tid == 0) {
        int r = 0;
        for (int w = 0; w < 16; w++) { woff[w] = r; r += wsum[w]; }
        woff[16] = r;
    }
    __syncthreads();
    int ex = woff[wave] + incl - s4;      // exclusive prefix at this thread's 1st elem
    int4 sg_pack;
    int* sgp = reinterpret_cast<int*>(&sg_pack);
#pragma unroll
    for (int i = 0; i < 4; i++) {
        int t = tid * 4 + i;
        sgp[i] = ex;                      // segment id = #boundaries strictly before t
        if (h[i]) { bpos[b * LL + ex] = t; ex++; }
    }
    *reinterpret_cast<int4*>(&segid[b * LL + tid * 4]) = sg_pack;

    if (tid == 0) {
        int total = woff[16];
        nseg[b] = total;
        float* out_sl = out + (size_t)BB * S * DD + (size_t)BB * LL;
        float* out_nb = out_sl + BB;
        out_nb[b] = (float)total;
        int denom = (S > 1) ? S : 1;
        out_sl[b] = (float)total / (float)denom;
    }
}

// ---------------------------------------------------------------------------
// K3: chunked segmented mean-pool (balanced; atomics only at chunk edges).
// ---------------------------------------------------------------------------
__global__ __launch_bounds__(256)
void k_pool2(const float* __restrict__ hidden, const int* __restrict__ nseg,
             const int* __restrict__ bpos, const int* __restrict__ segid,
             float* __restrict__ pooled, int S) {
    const int wave = threadIdx.x >> 6;
    const int lane = threadIdx.x & 63;
    const int g  = blockIdx.x * 4 + wave;      // 0 .. B*(LL/CH)-1
    const int b  = g / (LL / CH);
    const int c  = g % (LL / CH);
    const int t0 = c * CH;
    const int n  = nseg[b];
    const int* sgid = segid + b * LL;
    const int* bp   = bpos + b * LL;
    const float* hb = hidden + (size_t)b * LL * DD;
    float* pb = pooled + (size_t)b * S * DD;

    float4 a0 = {0.f, 0.f, 0.f, 0.f};
    float4 a1 = {0.f, 0.f, 0.f, 0.f};
    int cur = -1;
    int cur_start = 0;

    for (int t = t0; t < t0 + CH; t++) {
        int sg = sgid[t];
        if (sg != cur) {
            if (cur >= 0) {
                int real_end = (cur < n) ? bp[cur] : (LL - 1);
                float inv = 1.0f / (float)(real_end - cur_start + 1);
                float* dst = pb + (size_t)cur * DD;
                bool complete = (cur_start >= t0) && (t - 1 == real_end);
                if (complete) {
                    float4 r0 = {a0.x * inv, a0.y * inv, a0.z * inv, a0.w * inv};
                    float4 r1 = {a1.x * inv, a1.y * inv, a1.z * inv, a1.w * inv};
                    *reinterpret_cast<float4*>(&dst[lane * 4]) = r0;
                    *reinterpret_cast<float4*>(&dst[256 + lane * 4]) = r1;
                } else {
                    atomicAdd(&dst[lane * 4 + 0], a0.x * inv);
                    atomicAdd(&dst[lane * 4 + 1], a0.y * inv);
                    atomicAdd(&dst[lane * 4 + 2], a0.z * inv);
                    atomicAdd(&dst[lane * 4 + 3], a0.w * inv);
                    atomicAdd(&dst[256 + lane * 4 + 0], a1.x * inv);
                    atomicAdd(&dst[256 + lane * 4 + 1], a1.y * inv);
                    atomicAdd(&dst[256 + lane * 4 + 2], a1.z * inv);
                    atomicAdd(&dst[256 + lane * 4 + 3], a1.w * inv);
                }
            }
            if (sg < S) {
                cur = sg;
                cur_start = (sg > 0) ? bp[sg - 1] + 1 : 0;
                a0 = {0.f, 0.f, 0.f, 0.f};
                a1 = {0.f, 0.f, 0.f, 0.f};
            } else {
                cur = -1;
            }
        }
        if (cur >= 0) {
            float4 v0 = *reinterpret_cast<const float4*>(&hb[(size_t)t * DD + lane * 4]);
            float4 v1 = *reinterpret_cast<const float4*>(&hb[(size_t)t * DD + 256 + lane * 4]);
            a0.x += v0.x; a0.y += v0.y; a0.z += v0.z; a0.w += v0.w;
            a1.x += v1.x; a1.y += v1.y; a1.z += v1.z; a1.w += v1.w;
        }
    }
    if (cur >= 0) {
        int real_end = (cur < n) ? bp[cur] : (LL - 1);
        float inv = 1.0f / (float)(real_end - cur_start + 1);
        float* dst = pb + (size_t)cur * DD;
        bool complete = (cur_start >= t0) && (t0 + CH - 1 == real_end);
        if (complete) {
            float4 r0 = {a0.x * inv, a0.y * inv, a0.z * inv, a0.w * inv};
            float4 r1 = {a1.x * inv, a1.y * inv, a1.z * inv, a1.w * inv};
            *reinterpret_cast<float4*>(&dst[lane * 4]) = r0;
            *reinterpret_cast<float4*>(&dst[256 + lane * 4]) = r1;
        } else {
            atomicAdd(&dst[lane * 4 + 0], a0.x * inv);
            atomicAdd(&dst[lane * 4 + 1], a0.y * inv);
            atomicAdd(&dst[lane * 4 + 2], a0.z * inv);
            atomicAdd(&dst[lane * 4 + 3], a0.w * inv);
            atomicAdd(&dst[256 + lane * 4 + 0], a1.x * inv);
            atomicAdd(&dst[256 + lane * 4 + 1], a1.y * inv);
            atomicAdd(&dst[256 + lane * 4 + 2], a1.z * inv);
            atomicAdd(&dst[256 + lane * 4 + 3], a1.w * inv);
        }
    }
}

// ---------------------------------------------------------------------------
extern "C" void kernel_launch(void* const* d_in, const int* in_sizes, int n_in,
                              void* d_out, int out_size, void* d_ws, size_t ws_size,
                              hipStream_t stream) {
    const float* hidden  = (const float*)d_in[0];
    const float* lengths = (const float*)d_in[1];
    const float* W1      = (const float*)d_in[2];
    const float* b1      = (const float*)d_in[3];
    const float* W2      = (const float*)d_in[4];
    const float* b2      = (const float*)d_in[5];
    float* out           = (float*)d_out;

    const int S = (out_size - BB * LL - 2 * BB) / (BB * DD);

    float* logits = (float*)d_ws;                                     // B*L f32
    int*   bpos   = (int*)((char*)d_ws + (size_t)BB * LL * 4);        // B*L i32
    int*   segid  = (int*)((char*)d_ws + (size_t)2 * BB * LL * 4);    // B*L i32
    int*   nseg   = (int*)((char*)d_ws + (size_t)3 * BB * LL * 4);    // B i32
    unsigned short* wt_hi = (unsigned short*)((char*)d_ws + (size_t)3 * BB * LL * 4 + 1024);
    unsigned short* wt_lo = wt_hi + (size_t)DD * DD;

    hipMemsetAsync(out, 0, (size_t)BB * S * DD * sizeof(float), stream);
    hipMemsetAsync(logits, 0, (size_t)BB * LL * sizeof(float), stream);

    k_split<<<128, 256, 0, stream>>>(W1, wt_hi, wt_lo);
    k_mfma<<<1024, 512, 0, stream>>>(hidden, wt_hi, wt_lo, b1, W2, logits);
    k_bound<<<BB, 1024, 0, stream>>>(logits, lengths, b2, out, S, nseg, bpos, segid);
    k_pool2<<<(BB * (LL / CH)) / 4, 256, 0, stream>>>(hidden, nseg, bpos, segid, out, S);
}